// Round 1
// baseline (490.929 us; speedup 1.0000x reference)
//
#include <hip/hip_runtime.h>
#include <cstdint>

typedef __bf16 bf16;
typedef __attribute__((ext_vector_type(8))) __bf16 bf16x8;
typedef __attribute__((ext_vector_type(4))) __bf16 bf16x4;
typedef __attribute__((ext_vector_type(4))) float f32x4;

// Async global->LDS, 16B per lane. LDS dest = wave-uniform base + lane*16.
__device__ __forceinline__ void load_lds16(const void* g, void* l) {
  __builtin_amdgcn_global_load_lds(
      (const __attribute__((address_space(1))) unsigned int*)g,
      (__attribute__((address_space(3))) unsigned int*)l, 16, 0, 0);
}

// ---------------------------------------------------------------------------
// GEMM: C[M,N] = A[M,K] @ Bt[N,K]^T (+bias). 128x128 tile, BK=64, 256 thr.
// XOR-swizzled LDS granules (slot s of row r holds global granule s^(r&7)).
// ---------------------------------------------------------------------------
template <bool OUT_F32>
__global__ __launch_bounds__(256) void gemm_bt(
    const bf16* __restrict__ A, const bf16* __restrict__ Bt,
    const float* __restrict__ bias, void* __restrict__ Cv,
    int M, int N, int K) {
  __shared__ __align__(16) bf16 sA[128 * 64];
  __shared__ __align__(16) bf16 sB[128 * 64];
  const int t = threadIdx.x;
  const int w = t >> 6, lane = t & 63;
  const int quad = lane >> 4, l16 = lane & 15;
  const int wm = (w >> 1) * 64, wn = (w & 1) * 64;
  const int bm = blockIdx.y * 128, bn = blockIdx.x * 128;

  f32x4 acc[4][4] = {};
  const int srow = lane >> 3;  // row within 8-row chunk
  const int sg = lane & 7;     // granule slot

  for (int kt = 0; kt < (K >> 6); ++kt) {
    const int k0 = kt << 6;
#pragma unroll
    for (int c2 = 0; c2 < 4; ++c2) {
      int c = c2 * 4 + w;          // chunk 0..15 (8 rows each)
      int row = c * 8 + srow;      // 0..127
      int gg = sg ^ (row & 7);     // swizzled global granule
      load_lds16(A + (int64_t)(bm + row) * K + k0 + gg * 8, sA + c * 512);
      load_lds16(Bt + (int64_t)(bn + row) * K + k0 + gg * 8, sB + c * 512);
    }
    asm volatile("s_waitcnt vmcnt(0)" ::: "memory");
    __syncthreads();
#pragma unroll
    for (int ks = 0; ks < 2; ++ks) {
      bf16x8 af[4], bfr[4];
#pragma unroll
      for (int i = 0; i < 4; ++i) {
        int m = wm + i * 16 + l16;
        af[i] = *(const bf16x8*)(sA + m * 64 + (((ks * 4 + quad) ^ (l16 & 7)) * 8));
        int n = wn + i * 16 + l16;
        bfr[i] = *(const bf16x8*)(sB + n * 64 + (((ks * 4 + quad) ^ (l16 & 7)) * 8));
      }
#pragma unroll
      for (int i = 0; i < 4; ++i)
#pragma unroll
        for (int j = 0; j < 4; ++j)
          acc[i][j] = __builtin_amdgcn_mfma_f32_16x16x32_bf16(af[i], bfr[j],
                                                              acc[i][j], 0, 0, 0);
    }
    __syncthreads();
  }
  // epilogue: C/D layout col=lane&15, row=quad*4+reg
#pragma unroll
  for (int i = 0; i < 4; ++i) {
    int gm = bm + wm + i * 16 + quad * 4;
#pragma unroll
    for (int j = 0; j < 4; ++j) {
      int gn = bn + wn + j * 16 + l16;
      float bvv = bias ? bias[gn] : 0.0f;
#pragma unroll
      for (int r = 0; r < 4; ++r) {
        float v = acc[i][j][r] + bvv;
        if (OUT_F32)
          ((float*)Cv)[(int64_t)(gm + r) * N + gn] = v;
        else
          ((bf16*)Cv)[(int64_t)(gm + r) * N + gn] = (bf16)v;
      }
    }
  }
}

// ---------------------------------------------------------------------------
// Flash attention (causal GQA). Block = 128 q rows (4 waves x 32), 64-kv tiles.
// QKV: [4096][3072] bf16 (Q cols 0..2047, K 2048..2559, V 2560..3071)
// Vt:  [(b*4+g)*128 + d][2048] bf16
// Out: [4096][2048] bf16
// ---------------------------------------------------------------------------
__global__ __launch_bounds__(256) void attn(
    const bf16* __restrict__ QKV, const bf16* __restrict__ Vt,
    bf16* __restrict__ Out) {
  constexpr float SCALE = 0.08838834764831845f;  // 1/sqrt(128)
  constexpr float L2E = 1.44269504088896f;
  __shared__ __align__(16) bf16 sK[64 * 128];
  __shared__ __align__(16) bf16 sV[128 * 64];   // Vt tile: row=d, 64 kv cols
  __shared__ __align__(16) bf16 sP[128 * 72];   // padded rows (72*2B = 16B-mult)

  const int t = threadIdx.x;
  const int w = t >> 6, lane = t & 63;
  const int quad = lane >> 4, l16 = lane & 15;
  const int qt = blockIdx.x, h = blockIdx.y, b = blockIdx.z;
  const int g = h >> 2;
  const int qrow0 = qt * 128;
  const int wr0 = w * 32;

  // Q fragments in registers for the whole block
  bf16x8 qreg[2][4];
#pragma unroll
  for (int i = 0; i < 2; ++i)
#pragma unroll
    for (int ks = 0; ks < 4; ++ks) {
      int row = b * 2048 + qrow0 + wr0 + i * 16 + l16;
      int col = h * 128 + ks * 32 + quad * 8;
      qreg[i][ks] = *(const bf16x8*)(QKV + (int64_t)row * 3072 + col);
    }

  f32x4 oacc[2][8] = {};
  float mrow[2][4], lrow[2][4];
#pragma unroll
  for (int i = 0; i < 2; ++i)
#pragma unroll
    for (int r = 0; r < 4; ++r) { mrow[i][r] = -1e30f; lrow[i][r] = 0.f; }

  const int kbase = 2048 + g * 128;
  const bf16* vtb = Vt + (int64_t)((b * 4 + g) * 128) * 2048;
  const int niters = qt * 2 + 2;

  for (int it = 0; it < niters; ++it) {
    const int n0 = it * 64;
    // stage K tile (64 rows x 128 cols; 16 granules/row, swizzle low 3 bits)
    {
      int rowl = lane >> 4;  // 4 rows per 1KB chunk
#pragma unroll
      for (int c2 = 0; c2 < 4; ++c2) {
        int c = c2 * 4 + w;
        int row = c * 4 + rowl;
        int gg = (l16 & 8) | ((l16 ^ row) & 7);
        load_lds16(QKV + (int64_t)(b * 2048 + n0 + row) * 3072 + kbase + gg * 8,
                   sK + c * 512);
      }
      int rowv = lane >> 3;  // 8 rows per chunk
      int sg = lane & 7;
#pragma unroll
      for (int c2 = 0; c2 < 4; ++c2) {
        int c = c2 * 4 + w;
        int row = c * 8 + rowv;  // d index
        int gg = sg ^ (row & 7);
        load_lds16(vtb + (int64_t)row * 2048 + n0 + gg * 8, sV + c * 512);
      }
    }
    asm volatile("s_waitcnt vmcnt(0)" ::: "memory");
    __syncthreads();

    const bool active = n0 <= qrow0 + wr0 + 31;
    if (active) {
      // S = Q K^T
      f32x4 sacc[2][4] = {};
#pragma unroll
      for (int ks = 0; ks < 4; ++ks) {
        bf16x8 bk[4];
#pragma unroll
        for (int j = 0; j < 4; ++j) {
          int n = j * 16 + l16;
          bk[j] = *(const bf16x8*)(sK + n * 128 + (((ks * 4 + quad) ^ (n & 7)) * 8));
        }
#pragma unroll
        for (int i = 0; i < 2; ++i)
#pragma unroll
          for (int j = 0; j < 4; ++j)
            sacc[i][j] = __builtin_amdgcn_mfma_f32_16x16x32_bf16(
                qreg[i][ks], bk[j], sacc[i][j], 0, 0, 0);
      }
      // scale + causal mask
      const bool need_mask = (n0 + 63) > (qrow0 + wr0);
#pragma unroll
      for (int i = 0; i < 2; ++i)
#pragma unroll
        for (int j = 0; j < 4; ++j)
#pragma unroll
          for (int r = 0; r < 4; ++r) {
            float v = sacc[i][j][r] * SCALE;
            if (need_mask) {
              int nn = n0 + j * 16 + l16;
              int mm = qrow0 + wr0 + i * 16 + quad * 4 + r;
              if (nn > mm) v = -1e30f;
            }
            sacc[i][j][r] = v;
          }
      // online softmax per row (rows of a quad live in 16-lane groups)
#pragma unroll
      for (int i = 0; i < 2; ++i)
#pragma unroll
        for (int r = 0; r < 4; ++r) {
          float mx = fmaxf(fmaxf(sacc[i][0][r], sacc[i][1][r]),
                           fmaxf(sacc[i][2][r], sacc[i][3][r]));
          mx = fmaxf(mx, __shfl_xor(mx, 1));
          mx = fmaxf(mx, __shfl_xor(mx, 2));
          mx = fmaxf(mx, __shfl_xor(mx, 4));
          mx = fmaxf(mx, __shfl_xor(mx, 8));
          float mnew = fmaxf(mrow[i][r], mx);
          float alpha = exp2f((mrow[i][r] - mnew) * L2E);
          float rs = 0.f;
#pragma unroll
          for (int j = 0; j < 4; ++j) {
            float p = exp2f((sacc[i][j][r] - mnew) * L2E);
            sacc[i][j][r] = p;
            rs += p;
          }
          rs += __shfl_xor(rs, 1);
          rs += __shfl_xor(rs, 2);
          rs += __shfl_xor(rs, 4);
          rs += __shfl_xor(rs, 8);
          lrow[i][r] = lrow[i][r] * alpha + rs;
          mrow[i][r] = mnew;
#pragma unroll
          for (int dj = 0; dj < 8; ++dj) oacc[i][dj][r] *= alpha;
        }
      // P -> LDS (per-wave private rows)
#pragma unroll
      for (int i = 0; i < 2; ++i)
#pragma unroll
        for (int j = 0; j < 4; ++j)
#pragma unroll
          for (int r = 0; r < 4; ++r)
            sP[(wr0 + i * 16 + quad * 4 + r) * 72 + j * 16 + l16] =
                (bf16)sacc[i][j][r];
      asm volatile("s_waitcnt lgkmcnt(0)" ::: "memory");
      // O += P @ V
#pragma unroll
      for (int ks2 = 0; ks2 < 2; ++ks2) {
        bf16x8 ap[2], bv[8];
#pragma unroll
        for (int i = 0; i < 2; ++i)
          ap[i] = *(const bf16x8*)(sP + (wr0 + i * 16 + l16) * 72 + ks2 * 32 +
                                   quad * 8);
#pragma unroll
        for (int dj = 0; dj < 8; ++dj) {
          int d = dj * 16 + l16;
          bv[dj] = *(const bf16x8*)(sV + d * 64 +
                                    (((ks2 * 4 + quad) ^ (d & 7)) * 8));
        }
#pragma unroll
        for (int i = 0; i < 2; ++i)
#pragma unroll
          for (int dj = 0; dj < 8; ++dj)
            oacc[i][dj] = __builtin_amdgcn_mfma_f32_16x16x32_bf16(
                ap[i], bv[dj], oacc[i][dj], 0, 0, 0);
      }
    }
    __syncthreads();
  }
  // epilogue
#pragma unroll
  for (int i = 0; i < 2; ++i)
#pragma unroll
    for (int r = 0; r < 4; ++r) {
      float inv = 1.0f / lrow[i][r];
      int grow = b * 2048 + qrow0 + wr0 + i * 16 + quad * 4 + r;
#pragma unroll
      for (int dj = 0; dj < 8; ++dj)
        Out[(int64_t)grow * 2048 + h * 128 + dj * 16 + l16] =
            (bf16)(oacc[i][dj][r] * inv);
    }
}

// ---------------------------------------------------------------------------
// Helpers: conversions / transposes
// ---------------------------------------------------------------------------
__global__ void convert_x(const float* __restrict__ x, bf16* __restrict__ xb) {
  int idx = blockIdx.x * 256 + threadIdx.x;
  float4 v = ((const float4*)x)[idx];
  bf16x4 o = {(bf16)v.x, (bf16)v.y, (bf16)v.z, (bf16)v.w};
  ((bf16x4*)xb)[idx] = o;
}

// W [K][N] fp32 -> Wt [N][K] bf16. grid (N/32, K/32), block (32,8)
__global__ void transpose_w(const float* __restrict__ W, bf16* __restrict__ Wt,
                            int K, int N) {
  __shared__ float tile[32][33];
  int bx = blockIdx.x, by = blockIdx.y;
  int tx = threadIdx.x, ty = threadIdx.y;
#pragma unroll
  for (int q2 = 0; q2 < 4; ++q2)
    tile[ty + q2 * 8][tx] = W[(int64_t)(by * 32 + ty + q2 * 8) * N + bx * 32 + tx];
  __syncthreads();
#pragma unroll
  for (int q2 = 0; q2 < 4; ++q2)
    Wt[(int64_t)(bx * 32 + ty + q2 * 8) * K + by * 32 + tx] =
        (bf16)tile[tx][ty + q2 * 8];
}

// V cols of QKV -> Vt [(b*4+g)*128 + d][2048]. grid (4, 64, 8), block (32,8)
__global__ void transpose_v(const bf16* __restrict__ QKV, bf16* __restrict__ Vt) {
  __shared__ bf16 tile[32][34];
  int dt = blockIdx.x, tt = blockIdx.y, bg = blockIdx.z;
  int b = bg >> 2, g = bg & 3;
  int tx = threadIdx.x, ty = threadIdx.y;
#pragma unroll
  for (int q2 = 0; q2 < 4; ++q2) {
    int trow = tt * 32 + ty + q2 * 8;
    tile[ty + q2 * 8][tx] =
        QKV[(int64_t)(b * 2048 + trow) * 3072 + 2560 + g * 128 + dt * 32 + tx];
  }
  __syncthreads();
#pragma unroll
  for (int q2 = 0; q2 < 4; ++q2) {
    int d = dt * 32 + ty + q2 * 8;
    Vt[(int64_t)(bg * 128 + d) * 2048 + tt * 32 + tx] = tile[tx][ty + q2 * 8];
  }
}

__global__ void concat_bias(const float* __restrict__ bq,
                            const float* __restrict__ bk,
                            const float* __restrict__ bv,
                            float* __restrict__ o) {
  int i = blockIdx.x * 256 + threadIdx.x;
  if (i < 3072)
    o[i] = i < 2048 ? bq[i] : (i < 2560 ? bk[i - 2048] : bv[i - 2560]);
}

// ---------------------------------------------------------------------------
extern "C" void kernel_launch(void* const* d_in, const int* in_sizes, int n_in,
                              void* d_out, int out_size, void* d_ws,
                              size_t ws_size, hipStream_t stream) {
  const float* x = (const float*)d_in[0];
  const float* Wq = (const float*)d_in[1];
  const float* bq = (const float*)d_in[2];
  const float* Wk = (const float*)d_in[3];
  const float* bk = (const float*)d_in[4];
  const float* Wv = (const float*)d_in[5];
  const float* bv = (const float*)d_in[6];
  const float* Wo = (const float*)d_in[7];
  const float* bo = (const float*)d_in[8];
  float* out = (float*)d_out;

  char* ws = (char*)d_ws;
  bf16* xb = (bf16*)(ws);                              // 16.78 MB
  bf16* wqkvT = (bf16*)(ws + 16777216);                // 12.58 MB
  bf16* woT = (bf16*)(ws + 29360128);                  // 8.39 MB
  float* bqkv = (float*)(ws + 37748736);               // 12 KB
  bf16* qkv = (bf16*)(ws + 37761024);                  // 25.17 MB
  bf16* vt = (bf16*)(ws + 62926848);                   // 4.19 MB
  bf16* attnb = (bf16*)(ws + 67121152);                // 16.78 MB  (end ~83.9MB)

  convert_x<<<8192, 256, 0, stream>>>(x, xb);
  dim3 tb(32, 8);
  transpose_w<<<dim3(64, 64), tb, 0, stream>>>(Wq, wqkvT, 2048, 2048);
  transpose_w<<<dim3(16, 64), tb, 0, stream>>>(Wk, wqkvT + 2048 * 2048, 2048, 512);
  transpose_w<<<dim3(16, 64), tb, 0, stream>>>(Wv, wqkvT + 2560 * 2048, 2048, 512);
  transpose_w<<<dim3(64, 64), tb, 0, stream>>>(Wo, woT, 2048, 2048);
  concat_bias<<<12, 256, 0, stream>>>(bq, bk, bv, bqkv);

  // QKV = xb @ WqkvT^T + bqkv   [4096 x 3072]
  gemm_bt<false><<<dim3(24, 32), 256, 0, stream>>>(xb, wqkvT, bqkv, qkv, 4096,
                                                   3072, 2048);
  transpose_v<<<dim3(4, 64, 8), tb, 0, stream>>>(qkv, vt);
  attn<<<dim3(16, 16, 2), 256, 0, stream>>>(qkv, vt, attnb);
  // out = attnb @ WoT^T + bo    [4096 x 2048] fp32
  gemm_bt<true><<<dim3(16, 32), 256, 0, stream>>>(attnb, woT, bo, out, 4096,
                                                  2048, 2048);
}

// Round 2
// 384.871 us; speedup vs baseline: 1.2756x; 1.2756x over previous
//
#include <hip/hip_runtime.h>
#include <cstdint>

typedef __bf16 bf16;
typedef __attribute__((ext_vector_type(8))) __bf16 bf16x8;
typedef __attribute__((ext_vector_type(4))) __bf16 bf16x4;
typedef __attribute__((ext_vector_type(4))) float f32x4;

// Async global->LDS, 16B per lane. LDS dest = wave-uniform base + lane*16.
__device__ __forceinline__ void load_lds16(const void* g, void* l) {
  __builtin_amdgcn_global_load_lds(
      (const __attribute__((address_space(1))) unsigned int*)g,
      (__attribute__((address_space(3))) unsigned int*)l, 16, 0, 0);
}

__device__ __forceinline__ float fast_exp2(float x) {
  float r;
  asm volatile("v_exp_f32 %0, %1" : "=v"(r) : "v"(x));
  return r;
}

// ---------------------------------------------------------------------------
// GEMM: C[M,N] = A[M,K] @ Bt[N,K]^T (+bias). 128x128 tile, BK=64, 256 thr.
// XOR-swizzled LDS granules (slot s of row r holds global granule s^(r&7)).
// ---------------------------------------------------------------------------
template <bool OUT_F32>
__global__ __launch_bounds__(256) void gemm_bt(
    const bf16* __restrict__ A, const bf16* __restrict__ Bt,
    const float* __restrict__ bias, void* __restrict__ Cv,
    int M, int N, int K) {
  __shared__ __align__(16) bf16 sA[128 * 64];
  __shared__ __align__(16) bf16 sB[128 * 64];
  const int t = threadIdx.x;
  const int w = t >> 6, lane = t & 63;
  const int quad = lane >> 4, l16 = lane & 15;
  const int wm = (w >> 1) * 64, wn = (w & 1) * 64;
  const int bm = blockIdx.y * 128, bn = blockIdx.x * 128;

  f32x4 acc[4][4] = {};
  const int srow = lane >> 3;  // row within 8-row chunk
  const int sg = lane & 7;     // granule slot

  for (int kt = 0; kt < (K >> 6); ++kt) {
    const int k0 = kt << 6;
#pragma unroll
    for (int c2 = 0; c2 < 4; ++c2) {
      int c = c2 * 4 + w;          // chunk 0..15 (8 rows each)
      int row = c * 8 + srow;      // 0..127
      int gg = sg ^ (row & 7);     // swizzled global granule
      load_lds16(A + (int64_t)(bm + row) * K + k0 + gg * 8, sA + c * 512);
      load_lds16(Bt + (int64_t)(bn + row) * K + k0 + gg * 8, sB + c * 512);
    }
    asm volatile("s_waitcnt vmcnt(0)" ::: "memory");
    __syncthreads();
#pragma unroll
    for (int ks = 0; ks < 2; ++ks) {
      bf16x8 af[4], bfr[4];
#pragma unroll
      for (int i = 0; i < 4; ++i) {
        int m = wm + i * 16 + l16;
        af[i] = *(const bf16x8*)(sA + m * 64 + (((ks * 4 + quad) ^ (l16 & 7)) * 8));
        int n = wn + i * 16 + l16;
        bfr[i] = *(const bf16x8*)(sB + n * 64 + (((ks * 4 + quad) ^ (l16 & 7)) * 8));
      }
#pragma unroll
      for (int i = 0; i < 4; ++i)
#pragma unroll
        for (int j = 0; j < 4; ++j)
          acc[i][j] = __builtin_amdgcn_mfma_f32_16x16x32_bf16(af[i], bfr[j],
                                                              acc[i][j], 0, 0, 0);
    }
    __syncthreads();
  }
  // epilogue: C/D layout col=lane&15, row=quad*4+reg
#pragma unroll
  for (int i = 0; i < 4; ++i) {
    int gm = bm + wm + i * 16 + quad * 4;
#pragma unroll
    for (int j = 0; j < 4; ++j) {
      int gn = bn + wn + j * 16 + l16;
      float bvv = bias ? bias[gn] : 0.0f;
#pragma unroll
      for (int r = 0; r < 4; ++r) {
        float v = acc[i][j][r] + bvv;
        if (OUT_F32)
          ((float*)Cv)[(int64_t)(gm + r) * N + gn] = v;
        else
          ((bf16*)Cv)[(int64_t)(gm + r) * N + gn] = (bf16)v;
      }
    }
  }
}

// ---------------------------------------------------------------------------
// Flash attention (causal GQA), mirror-paired q-tiles, shared kv loop.
// Block = 256 thr (4 waves, 16 q-rows/wave/tile). blockIdx.x = p in [0,16):
// handles 64-row q-tiles p (A) and 31-p (B). Tile A active while it <= p.
// Double-buffered K/V staging via global_load_lds + raw s_barrier (no drain).
// P matrix overlays the retired K buffer (wave-private rows).
// QKV: [4096][3072] bf16 (Q 0..2047, K 2048..2559, V 2560..3071)
// Vt:  [(b*4+g)*128 + d][2048] bf16;  Out: [4096][2048] bf16
// ---------------------------------------------------------------------------
__global__ __launch_bounds__(256, 2) void attn(
    const bf16* __restrict__ QKV, const bf16* __restrict__ Vt,
    bf16* __restrict__ Out) {
  constexpr float SCALE = 0.08838834764831845f;  // 1/sqrt(128)
  constexpr float L2E = 1.44269504088896f;
  __shared__ __align__(16) bf16 sK[2][64 * 128];
  __shared__ __align__(16) bf16 sV[2][128 * 64];

  const int t = threadIdx.x;
  const int w = t >> 6, lane = t & 63;
  const int quad = lane >> 4, l16 = lane & 15;
  const int p = blockIdx.x, h = blockIdx.y, b = blockIdx.z;
  const int g = h >> 2;
  const int wr0 = w * 16;
  const int kbase = 2048 + g * 128;
  const bf16* vtb = Vt + (int64_t)((b * 4 + g) * 128) * 2048;
  const int rk = lane >> 4, rv = lane >> 3, sgv = lane & 7;
  const int qrow0A = p * 64, qrow0B = (31 - p) * 64;
  const int niters = 32 - p;

  // Q fragments for both tiles, in registers for the whole kernel
  bf16x8 qreg[2][4];
#pragma unroll
  for (int u = 0; u < 2; ++u) {
    int qr = (u == 0 ? qrow0A : qrow0B);
#pragma unroll
    for (int ks = 0; ks < 4; ++ks)
      qreg[u][ks] = *(const bf16x8*)(QKV +
          (int64_t)(b * 2048 + qr + wr0 + l16) * 3072 + h * 128 + ks * 32 +
          quad * 8);
  }

  f32x4 oacc[2][8] = {};
  float mrow[2][4], lrow[2][4];
#pragma unroll
  for (int u = 0; u < 2; ++u)
#pragma unroll
    for (int r = 0; r < 4; ++r) { mrow[u][r] = -1e30f; lrow[u][r] = 0.f; }

  auto stage = [&](int n0, bf16* sKb, bf16* sVb) {
#pragma unroll
    for (int c2 = 0; c2 < 4; ++c2) {
      int c = c2 * 4 + w;
      int rowk = c * 4 + rk;  // 0..63 (kv)
      int ggk = (l16 & 8) | ((l16 ^ rowk) & 7);
      load_lds16(QKV + (int64_t)(b * 2048 + n0 + rowk) * 3072 + kbase + ggk * 8,
                 sKb + c * 512);
      int rowv = c * 8 + rv;  // 0..127 (d)
      int ggv = sgv ^ (rowv & 7);
      load_lds16(vtb + (int64_t)rowv * 2048 + n0 + ggv * 8, sVb + c * 512);
    }
  };

  f32x4 sacc[2][4];

  stage(0, sK[0], sV[0]);

  for (int it = 0; it < niters; ++it) {
    const int cur = it & 1;
    const int n0 = it * 64;
    bf16* sKc = sK[cur];
    bf16* sVc = sV[cur];
    const bool actA = (it <= p);

    // staged tile ready across all waves; prefetch in flight stays in flight
    asm volatile("s_waitcnt vmcnt(0)\n\ts_barrier" ::: "memory");
    if (it + 1 < niters) stage(n0 + 64, sK[cur ^ 1], sV[cur ^ 1]);

    // ---- S = Q K^T ----
#pragma unroll
    for (int u = 0; u < 2; ++u)
#pragma unroll
      for (int j = 0; j < 4; ++j) sacc[u][j] = f32x4{0.f, 0.f, 0.f, 0.f};
    if (actA) {
#pragma unroll
      for (int ks = 0; ks < 4; ++ks)
#pragma unroll
        for (int j = 0; j < 4; ++j) {
          int n = j * 16 + l16;
          int G = ks * 4 + quad;
          int slot = (G & 8) | ((G ^ n) & 7);
          bf16x8 bk = *(const bf16x8*)(sKc + n * 128 + slot * 8);
          sacc[0][j] = __builtin_amdgcn_mfma_f32_16x16x32_bf16(
              qreg[0][ks], bk, sacc[0][j], 0, 0, 0);
          sacc[1][j] = __builtin_amdgcn_mfma_f32_16x16x32_bf16(
              qreg[1][ks], bk, sacc[1][j], 0, 0, 0);
        }
    } else {
#pragma unroll
      for (int ks = 0; ks < 4; ++ks)
#pragma unroll
        for (int j = 0; j < 4; ++j) {
          int n = j * 16 + l16;
          int G = ks * 4 + quad;
          int slot = (G & 8) | ((G ^ n) & 7);
          bf16x8 bk = *(const bf16x8*)(sKc + n * 128 + slot * 8);
          sacc[1][j] = __builtin_amdgcn_mfma_f32_16x16x32_bf16(
              qreg[1][ks], bk, sacc[1][j], 0, 0, 0);
        }
    }

    // all waves done reading K tile; P may now overwrite it (wave-priv rows)
    asm volatile("s_barrier" ::: "memory");

    // ---- online softmax + P write (into retired K buffer) ----
    auto softmax_tile = [&](int u, bool last, int qrow0u) {
#pragma unroll
      for (int j = 0; j < 4; ++j)
#pragma unroll
        for (int r = 0; r < 4; ++r) {
          float v = sacc[u][j][r] * SCALE;
          if (last) {
            int nn = n0 + j * 16 + l16;
            int mm = qrow0u + wr0 + quad * 4 + r;
            if (nn > mm) v = -1e30f;
          }
          sacc[u][j][r] = v;
        }
#pragma unroll
      for (int r = 0; r < 4; ++r) {
        float mx = fmaxf(fmaxf(sacc[u][0][r], sacc[u][1][r]),
                         fmaxf(sacc[u][2][r], sacc[u][3][r]));
        mx = fmaxf(mx, __shfl_xor(mx, 1));
        mx = fmaxf(mx, __shfl_xor(mx, 2));
        mx = fmaxf(mx, __shfl_xor(mx, 4));
        mx = fmaxf(mx, __shfl_xor(mx, 8));
        float mnew = fmaxf(mrow[u][r], mx);
        float alpha = fast_exp2((mrow[u][r] - mnew) * L2E);
        float rs = 0.f;
#pragma unroll
        for (int j = 0; j < 4; ++j) {
          float pv = fast_exp2((sacc[u][j][r] - mnew) * L2E);
          sacc[u][j][r] = pv;
          rs += pv;
        }
        rs += __shfl_xor(rs, 1);
        rs += __shfl_xor(rs, 2);
        rs += __shfl_xor(rs, 4);
        rs += __shfl_xor(rs, 8);
        lrow[u][r] = lrow[u][r] * alpha + rs;
        mrow[u][r] = mnew;
#pragma unroll
        for (int dj = 0; dj < 8; ++dj) oacc[u][dj][r] *= alpha;
      }
      bf16* sPu = sKc + u * 4096;
#pragma unroll
      for (int j = 0; j < 4; ++j) {
        int c8 = j * 2 + (l16 >> 3);
        int cl = l16 & 7;
#pragma unroll
        for (int r = 0; r < 4; ++r) {
          int rp = wr0 + quad * 4 + r;
          sPu[rp * 64 + ((c8 ^ (rp & 7)) * 8) + cl] = (bf16)sacc[u][j][r];
        }
      }
    };
    if (actA) softmax_tile(0, it == p, qrow0A);
    softmax_tile(1, it == niters - 1, qrow0B);

    // own P writes visible to own reads
    asm volatile("s_waitcnt lgkmcnt(0)" ::: "memory");

    // ---- O += P @ V ----
    if (actA) {
#pragma unroll
      for (int ks2 = 0; ks2 < 2; ++ks2) {
        int rp = wr0 + l16;
        int G = ks2 * 4 + quad;
        int po = rp * 64 + ((G ^ (rp & 7)) * 8);
        bf16x8 apA = *(const bf16x8*)(sKc + po);
        bf16x8 apB = *(const bf16x8*)(sKc + 4096 + po);
#pragma unroll
        for (int dj = 0; dj < 8; ++dj) {
          int d = dj * 16 + l16;
          bf16x8 bv = *(const bf16x8*)(sVc + d * 64 + ((G ^ (d & 7)) * 8));
          oacc[0][dj] = __builtin_amdgcn_mfma_f32_16x16x32_bf16(apA, bv,
                                                               oacc[0][dj], 0, 0, 0);
          oacc[1][dj] = __builtin_amdgcn_mfma_f32_16x16x32_bf16(apB, bv,
                                                               oacc[1][dj], 0, 0, 0);
        }
      }
    } else {
#pragma unroll
      for (int ks2 = 0; ks2 < 2; ++ks2) {
        int rp = wr0 + l16;
        int G = ks2 * 4 + quad;
        bf16x8 apB = *(const bf16x8*)(sKc + 4096 + rp * 64 + ((G ^ (rp & 7)) * 8));
#pragma unroll
        for (int dj = 0; dj < 8; ++dj) {
          int d = dj * 16 + l16;
          bf16x8 bv = *(const bf16x8*)(sVc + d * 64 + ((G ^ (d & 7)) * 8));
          oacc[1][dj] = __builtin_amdgcn_mfma_f32_16x16x32_bf16(apB, bv,
                                                               oacc[1][dj], 0, 0, 0);
        }
      }
    }
  }

  // ---- epilogue ----
#pragma unroll
  for (int u = 0; u < 2; ++u) {
    int qrow0u = (u == 0 ? qrow0A : qrow0B);
#pragma unroll
    for (int r = 0; r < 4; ++r) {
      float inv = 1.0f / lrow[u][r];
      int64_t grow = b * 2048 + qrow0u + wr0 + quad * 4 + r;
#pragma unroll
      for (int dj = 0; dj < 8; ++dj)
        Out[grow * 2048 + h * 128 + dj * 16 + l16] = (bf16)(oacc[u][dj][r] * inv);
    }
  }
}

// ---------------------------------------------------------------------------
// Helpers: conversions / transposes
// ---------------------------------------------------------------------------
__global__ void convert_x(const float* __restrict__ x, bf16* __restrict__ xb) {
  int idx = blockIdx.x * 256 + threadIdx.x;
  float4 v = ((const float4*)x)[idx];
  bf16x4 o = {(bf16)v.x, (bf16)v.y, (bf16)v.z, (bf16)v.w};
  ((bf16x4*)xb)[idx] = o;
}

// W [K][N] fp32 -> Wt [N][K] bf16. grid (N/32, K/32), block (32,8)
__global__ void transpose_w(const float* __restrict__ W, bf16* __restrict__ Wt,
                            int K, int N) {
  __shared__ float tile[32][33];
  int bx = blockIdx.x, by = blockIdx.y;
  int tx = threadIdx.x, ty = threadIdx.y;
#pragma unroll
  for (int q2 = 0; q2 < 4; ++q2)
    tile[ty + q2 * 8][tx] = W[(int64_t)(by * 32 + ty + q2 * 8) * N + bx * 32 + tx];
  __syncthreads();
#pragma unroll
  for (int q2 = 0; q2 < 4; ++q2)
    Wt[(int64_t)(bx * 32 + ty + q2 * 8) * K + by * 32 + tx] =
        (bf16)tile[tx][ty + q2 * 8];
}

// V cols of QKV -> Vt [(b*4+g)*128 + d][2048]. grid (4, 64, 8), block (32,8)
__global__ void transpose_v(const bf16* __restrict__ QKV, bf16* __restrict__ Vt) {
  __shared__ bf16 tile[32][34];
  int dt = blockIdx.x, tt = blockIdx.y, bg = blockIdx.z;
  int b = bg >> 2, g = bg & 3;
  int tx = threadIdx.x, ty = threadIdx.y;
#pragma unroll
  for (int q2 = 0; q2 < 4; ++q2) {
    int trow = tt * 32 + ty + q2 * 8;
    tile[ty + q2 * 8][tx] =
        QKV[(int64_t)(b * 2048 + trow) * 3072 + 2560 + g * 128 + dt * 32 + tx];
  }
  __syncthreads();
#pragma unroll
  for (int q2 = 0; q2 < 4; ++q2) {
    int d = dt * 32 + ty + q2 * 8;
    Vt[(int64_t)(bg * 128 + d) * 2048 + tt * 32 + tx] = tile[tx][ty + q2 * 8];
  }
}

__global__ void concat_bias(const float* __restrict__ bq,
                            const float* __restrict__ bk,
                            const float* __restrict__ bv,
                            float* __restrict__ o) {
  int i = blockIdx.x * 256 + threadIdx.x;
  if (i < 3072)
    o[i] = i < 2048 ? bq[i] : (i < 2560 ? bk[i - 2048] : bv[i - 2560]);
}

// ---------------------------------------------------------------------------
extern "C" void kernel_launch(void* const* d_in, const int* in_sizes, int n_in,
                              void* d_out, int out_size, void* d_ws,
                              size_t ws_size, hipStream_t stream) {
  const float* x = (const float*)d_in[0];
  const float* Wq = (const float*)d_in[1];
  const float* bq = (const float*)d_in[2];
  const float* Wk = (const float*)d_in[3];
  const float* bk = (const float*)d_in[4];
  const float* Wv = (const float*)d_in[5];
  const float* bv = (const float*)d_in[6];
  const float* Wo = (const float*)d_in[7];
  const float* bo = (const float*)d_in[8];
  float* out = (float*)d_out;

  char* ws = (char*)d_ws;
  bf16* xb = (bf16*)(ws);                              // 16.78 MB
  bf16* wqkvT = (bf16*)(ws + 16777216);                // 12.58 MB
  bf16* woT = (bf16*)(ws + 29360128);                  // 8.39 MB
  float* bqkv = (float*)(ws + 37748736);               // 12 KB
  bf16* qkv = (bf16*)(ws + 37761024);                  // 25.17 MB
  bf16* vt = (bf16*)(ws + 62926848);                   // 4.19 MB
  bf16* attnb = (bf16*)(ws + 67121152);                // 16.78 MB  (end ~83.9MB)

  convert_x<<<8192, 256, 0, stream>>>(x, xb);
  dim3 tb(32, 8);
  transpose_w<<<dim3(64, 64), tb, 0, stream>>>(Wq, wqkvT, 2048, 2048);
  transpose_w<<<dim3(16, 64), tb, 0, stream>>>(Wk, wqkvT + 2048 * 2048, 2048, 512);
  transpose_w<<<dim3(16, 64), tb, 0, stream>>>(Wv, wqkvT + 2560 * 2048, 2048, 512);
  transpose_w<<<dim3(64, 64), tb, 0, stream>>>(Wo, woT, 2048, 2048);
  concat_bias<<<12, 256, 0, stream>>>(bq, bk, bv, bqkv);

  // QKV = xb @ WqkvT^T + bqkv   [4096 x 3072]
  gemm_bt<false><<<dim3(24, 32), 256, 0, stream>>>(xb, wqkvT, bqkv, qkv, 4096,
                                                   3072, 2048);
  transpose_v<<<dim3(4, 64, 8), tb, 0, stream>>>(qkv, vt);
  // mirror-paired flash attention: blockIdx.x = pair index p
  attn<<<dim3(16, 16, 2), 256, 0, stream>>>(qkv, vt, attnb);
  // out = attnb @ WoT^T + bo    [4096 x 2048] fp32
  gemm_bt<true><<<dim3(16, 32), 256, 0, stream>>>(attnb, woT, bo, out, 4096,
                                                  2048, 2048);
}

// Round 3
// 319.131 us; speedup vs baseline: 1.5383x; 1.2060x over previous
//
#include <hip/hip_runtime.h>
#include <cstdint>

typedef __bf16 bf16;
typedef __attribute__((ext_vector_type(8))) __bf16 bf16x8;
typedef __attribute__((ext_vector_type(4))) __bf16 bf16x4;
typedef __attribute__((ext_vector_type(4))) float f32x4;

// Async global->LDS, 16B per lane. LDS dest = wave-uniform base + lane*16.
__device__ __forceinline__ void load_lds16(const void* g, void* l) {
  __builtin_amdgcn_global_load_lds(
      (const __attribute__((address_space(1))) unsigned int*)g,
      (__attribute__((address_space(3))) unsigned int*)l, 16, 0, 0);
}

__device__ __forceinline__ float fast_exp2(float x) {
  float r;
  asm volatile("v_exp_f32 %0, %1" : "=v"(r) : "v"(x));
  return r;
}

// ---------------------------------------------------------------------------
// GEMM: C[M,N] = A[M,K] @ Bt[N,K]^T (+bias). 128x128 tile, BK=64, 256 thr.
// ---------------------------------------------------------------------------
template <bool OUT_F32>
__global__ __launch_bounds__(256) void gemm_bt(
    const bf16* __restrict__ A, const bf16* __restrict__ Bt,
    const float* __restrict__ bias, void* __restrict__ Cv,
    int M, int N, int K) {
  __shared__ __align__(16) bf16 sA[128 * 64];
  __shared__ __align__(16) bf16 sB[128 * 64];
  const int t = threadIdx.x;
  const int w = t >> 6, lane = t & 63;
  const int quad = lane >> 4, l16 = lane & 15;
  const int wm = (w >> 1) * 64, wn = (w & 1) * 64;
  const int bm = blockIdx.y * 128, bn = blockIdx.x * 128;

  f32x4 acc[4][4] = {};
  const int srow = lane >> 3;
  const int sg = lane & 7;

  for (int kt = 0; kt < (K >> 6); ++kt) {
    const int k0 = kt << 6;
#pragma unroll
    for (int c2 = 0; c2 < 4; ++c2) {
      int c = c2 * 4 + w;
      int row = c * 8 + srow;
      int gg = sg ^ (row & 7);
      load_lds16(A + (int64_t)(bm + row) * K + k0 + gg * 8, sA + c * 512);
      load_lds16(Bt + (int64_t)(bn + row) * K + k0 + gg * 8, sB + c * 512);
    }
    asm volatile("s_waitcnt vmcnt(0)" ::: "memory");
    __syncthreads();
#pragma unroll
    for (int ks = 0; ks < 2; ++ks) {
      bf16x8 af[4], bfr[4];
#pragma unroll
      for (int i = 0; i < 4; ++i) {
        int m = wm + i * 16 + l16;
        af[i] = *(const bf16x8*)(sA + m * 64 + (((ks * 4 + quad) ^ (l16 & 7)) * 8));
        int n = wn + i * 16 + l16;
        bfr[i] = *(const bf16x8*)(sB + n * 64 + (((ks * 4 + quad) ^ (l16 & 7)) * 8));
      }
#pragma unroll
      for (int i = 0; i < 4; ++i)
#pragma unroll
        for (int j = 0; j < 4; ++j)
          acc[i][j] = __builtin_amdgcn_mfma_f32_16x16x32_bf16(af[i], bfr[j],
                                                              acc[i][j], 0, 0, 0);
    }
    __syncthreads();
  }
#pragma unroll
  for (int i = 0; i < 4; ++i) {
    int gm = bm + wm + i * 16 + quad * 4;
#pragma unroll
    for (int j = 0; j < 4; ++j) {
      int gn = bn + wn + j * 16 + l16;
      float bvv = bias ? bias[gn] : 0.0f;
#pragma unroll
      for (int r = 0; r < 4; ++r) {
        float v = acc[i][j][r] + bvv;
        if (OUT_F32)
          ((float*)Cv)[(int64_t)(gm + r) * N + gn] = v;
        else
          ((bf16*)Cv)[(int64_t)(gm + r) * N + gn] = (bf16)v;
      }
    }
  }
}

// ---------------------------------------------------------------------------
// Flash attention (causal GQA), mirror-paired q-tiles, TRANSPOSED scores.
// S^T = K·Q^T  (C-layout: col=q=lane&15 -> softmax reductions are in-lane
// + 2 shuffles), P^T kept in separate sP (no post-QK^T barrier),
// O^T = V^T·P^T (C: col=q, row=d; alpha rescale is a per-lane scalar).
// Block = 4 waves; wave owns 16 q rows of tile A (p) and tile B (31-p).
// ---------------------------------------------------------------------------
__global__ __launch_bounds__(256, 2) void attn(
    const bf16* __restrict__ QKV, const bf16* __restrict__ Vt,
    bf16* __restrict__ Out) {
  constexpr float CC = 0.08838834764831845f * 1.44269504088896f;  // scale*log2e
  __shared__ __align__(16) bf16 sK[2][64 * 128];
  __shared__ __align__(16) bf16 sV[2][128 * 64];
  __shared__ __align__(16) bf16 sP[128 * 64];  // [q_local][kv], 16B-swizzled

  const int t = threadIdx.x;
  const int w = t >> 6, lane = t & 63;
  const int quad = lane >> 4, l16 = lane & 15;
  const int p = blockIdx.x, h = blockIdx.y, b = blockIdx.z;
  const int g = h >> 2;
  const int wr0 = w * 16;
  const int kbase = 2048 + g * 128;
  const bf16* vtb = Vt + (int64_t)((b * 4 + g) * 128) * 2048;
  const int rk = lane >> 4, rv = lane >> 3, sgv = lane & 7;
  const int qrow0A = p * 64, qrow0B = (31 - p) * 64;
  const int niters = 32 - p;

  // Q fragments (same registers serve as B-operand for S^T = K Q^T)
  bf16x8 qreg[2][4];
#pragma unroll
  for (int u = 0; u < 2; ++u) {
    int qr = (u == 0 ? qrow0A : qrow0B);
#pragma unroll
    for (int ks = 0; ks < 4; ++ks)
      qreg[u][ks] = *(const bf16x8*)(QKV +
          (int64_t)(b * 2048 + qr + wr0 + l16) * 3072 + h * 128 + ks * 32 +
          quad * 8);
  }

  f32x4 oacc[2][8] = {};
  float mrow[2] = {-3.0e38f, -3.0e38f};
  float lrow[2] = {0.f, 0.f};

  auto stage = [&](int n0, bf16* sKb, bf16* sVb) {
#pragma unroll
    for (int c2 = 0; c2 < 4; ++c2) {
      int c = c2 * 4 + w;
      int rowk = c * 4 + rk;
      int ggk = (l16 & 8) | ((l16 ^ rowk) & 7);
      load_lds16(QKV + (int64_t)(b * 2048 + n0 + rowk) * 3072 + kbase + ggk * 8,
                 sKb + c * 512);
      int rowv = c * 8 + rv;
      int ggv = sgv ^ (rowv & 7);
      load_lds16(vtb + (int64_t)rowv * 2048 + n0 + ggv * 8, sVb + c * 512);
    }
  };

  stage(0, sK[0], sV[0]);

  // sP element offsets for this lane (row = q_local, swizzled kv granules)
  const int prowA = wr0 + l16;          // u=0 rows 0..63
  const int prowB = 64 + wr0 + l16;     // u=1 rows 64..127

  for (int it = 0; it < niters; ++it) {
    const int cur = it & 1;
    const int n0 = it * 64;
    bf16* sKc = sK[cur];
    bf16* sVc = sV[cur];
    const bool actA = (it <= p);

    asm volatile("s_waitcnt vmcnt(0)\n\ts_barrier" ::: "memory");
    if (it + 1 < niters) stage(n0 + 64, sK[cur ^ 1], sV[cur ^ 1]);

    // ---- S^T = K Q^T : sacc[u][mj], row=kv=mj*16+quad*4+r, col=q=l16 ----
    f32x4 sacc[2][4] = {};
    if (actA) {
#pragma unroll
      for (int ks = 0; ks < 4; ++ks) {
        bf16x8 ak[4];
#pragma unroll
        for (int mj = 0; mj < 4; ++mj) {
          int kvr = mj * 16 + l16;
          int G = ks * 4 + quad;
          int slot = (G & 8) | ((G ^ kvr) & 7);
          ak[mj] = *(const bf16x8*)(sKc + kvr * 128 + slot * 8);
        }
#pragma unroll
        for (int mj = 0; mj < 4; ++mj) {
          sacc[0][mj] = __builtin_amdgcn_mfma_f32_16x16x32_bf16(
              ak[mj], qreg[0][ks], sacc[0][mj], 0, 0, 0);
          sacc[1][mj] = __builtin_amdgcn_mfma_f32_16x16x32_bf16(
              ak[mj], qreg[1][ks], sacc[1][mj], 0, 0, 0);
        }
      }
    } else {
#pragma unroll
      for (int ks = 0; ks < 4; ++ks) {
        bf16x8 ak[4];
#pragma unroll
        for (int mj = 0; mj < 4; ++mj) {
          int kvr = mj * 16 + l16;
          int G = ks * 4 + quad;
          int slot = (G & 8) | ((G ^ kvr) & 7);
          ak[mj] = *(const bf16x8*)(sKc + kvr * 128 + slot * 8);
        }
#pragma unroll
        for (int mj = 0; mj < 4; ++mj)
          sacc[1][mj] = __builtin_amdgcn_mfma_f32_16x16x32_bf16(
              ak[mj], qreg[1][ks], sacc[1][mj], 0, 0, 0);
      }
    }

    // ---- online softmax (raw scores; scale folded into CC) + P^T write ----
    auto softmax_u = [&](int u, bool last, int qrow0u, int prow) {
      if (last) {
        int q = qrow0u + wr0 + l16;
#pragma unroll
        for (int mj = 0; mj < 4; ++mj)
#pragma unroll
          for (int r = 0; r < 4; ++r) {
            int kv = n0 + mj * 16 + quad * 4 + r;
            if (kv > q) sacc[u][mj][r] = -3.0e38f;
          }
      }
      f32x4 m01, m23;
#pragma unroll
      for (int r = 0; r < 4; ++r) {
        m01[r] = fmaxf(sacc[u][0][r], sacc[u][1][r]);
        m23[r] = fmaxf(sacc[u][2][r], sacc[u][3][r]);
      }
      float mx = fmaxf(fmaxf(fmaxf(m01[0], m01[1]), fmaxf(m01[2], m01[3])),
                       fmaxf(fmaxf(m23[0], m23[1]), fmaxf(m23[2], m23[3])));
      mx = fmaxf(mx, __shfl_xor(mx, 16));
      mx = fmaxf(mx, __shfl_xor(mx, 32));
      float mnew = fmaxf(mrow[u], mx);
      float alpha = fast_exp2((mrow[u] - mnew) * CC);
      float rs = 0.f;
#pragma unroll
      for (int mj = 0; mj < 4; ++mj) {
        bf16x4 p4;
#pragma unroll
        for (int r = 0; r < 4; ++r) {
          float pv = fast_exp2((sacc[u][mj][r] - mnew) * CC);
          rs += pv;
          p4[r] = (bf16)pv;
        }
        // write 8B at [prow][kv = mj*16+quad*4], 16B-granule xor swizzle
        int g16 = mj * 2 + (quad >> 1);
        int off = prow * 64 + ((g16 ^ (prow & 7)) * 8) + (quad & 1) * 4;
        *(bf16x4*)(sP + off) = p4;
      }
      rs += __shfl_xor(rs, 16);
      rs += __shfl_xor(rs, 32);
      lrow[u] = lrow[u] * alpha + rs;
      mrow[u] = mnew;
#pragma unroll
      for (int dj = 0; dj < 8; ++dj)
#pragma unroll
        for (int r = 0; r < 4; ++r) oacc[u][dj][r] *= alpha;
    };
    if (actA) softmax_u(0, it == p, qrow0A, prowA);
    softmax_u(1, it == niters - 1, qrow0B, prowB);

    // own P^T writes visible to own reads (wave-private rows; no barrier)
    asm volatile("s_waitcnt lgkmcnt(0)" ::: "memory");

    // ---- O^T += V^T P^T : oacc[u][dj], row=d=dj*16+quad*4+r, col=q=l16 ----
#pragma unroll
    for (int ks2 = 0; ks2 < 2; ++ks2) {
      int G = ks2 * 4 + quad;
      bf16x8 bpA, bpB;
      if (actA)
        bpA = *(const bf16x8*)(sP + prowA * 64 + ((G ^ (prowA & 7)) * 8));
      bpB = *(const bf16x8*)(sP + prowB * 64 + ((G ^ (prowB & 7)) * 8));
      bf16x8 av[8];
#pragma unroll
      for (int dj = 0; dj < 8; ++dj) {
        int d = dj * 16 + l16;
        av[dj] = *(const bf16x8*)(sVc + d * 64 + ((G ^ (d & 7)) * 8));
      }
      if (actA) {
#pragma unroll
        for (int dj = 0; dj < 8; ++dj) {
          oacc[0][dj] = __builtin_amdgcn_mfma_f32_16x16x32_bf16(
              av[dj], bpA, oacc[0][dj], 0, 0, 0);
          oacc[1][dj] = __builtin_amdgcn_mfma_f32_16x16x32_bf16(
              av[dj], bpB, oacc[1][dj], 0, 0, 0);
        }
      } else {
#pragma unroll
        for (int dj = 0; dj < 8; ++dj)
          oacc[1][dj] = __builtin_amdgcn_mfma_f32_16x16x32_bf16(
              av[dj], bpB, oacc[1][dj], 0, 0, 0);
      }
    }
  }

  // ---- epilogue: O^T -> Out[q][h*128+d], 8B stores ----
#pragma unroll
  for (int u = 0; u < 2; ++u) {
    int qrow0u = (u == 0 ? qrow0A : qrow0B);
    float inv = 1.0f / lrow[u];
    int64_t grow = b * 2048 + qrow0u + wr0 + l16;
#pragma unroll
    for (int dj = 0; dj < 8; ++dj) {
      bf16x4 o4;
#pragma unroll
      for (int r = 0; r < 4; ++r) o4[r] = (bf16)(oacc[u][dj][r] * inv);
      *(bf16x4*)(Out + grow * 2048 + h * 128 + dj * 16 + quad * 4) = o4;
    }
  }
}

// ---------------------------------------------------------------------------
// Helpers
// ---------------------------------------------------------------------------
__global__ void convert_x(const float* __restrict__ x, bf16* __restrict__ xb) {
  int idx = blockIdx.x * 256 + threadIdx.x;
  float4 v = ((const float4*)x)[idx];
  bf16x4 o = {(bf16)v.x, (bf16)v.y, (bf16)v.z, (bf16)v.w};
  ((bf16x4*)xb)[idx] = o;
}

__global__ void transpose_w(const float* __restrict__ W, bf16* __restrict__ Wt,
                            int K, int N) {
  __shared__ float tile[32][33];
  int bx = blockIdx.x, by = blockIdx.y;
  int tx = threadIdx.x, ty = threadIdx.y;
#pragma unroll
  for (int q2 = 0; q2 < 4; ++q2)
    tile[ty + q2 * 8][tx] = W[(int64_t)(by * 32 + ty + q2 * 8) * N + bx * 32 + tx];
  __syncthreads();
#pragma unroll
  for (int q2 = 0; q2 < 4; ++q2)
    Wt[(int64_t)(bx * 32 + ty + q2 * 8) * K + by * 32 + tx] =
        (bf16)tile[tx][ty + q2 * 8];
}

__global__ void transpose_v(const bf16* __restrict__ QKV, bf16* __restrict__ Vt) {
  __shared__ bf16 tile[32][34];
  int dt = blockIdx.x, tt = blockIdx.y, bg = blockIdx.z;
  int b = bg >> 2, g = bg & 3;
  int tx = threadIdx.x, ty = threadIdx.y;
#pragma unroll
  for (int q2 = 0; q2 < 4; ++q2) {
    int trow = tt * 32 + ty + q2 * 8;
    tile[ty + q2 * 8][tx] =
        QKV[(int64_t)(b * 2048 + trow) * 3072 + 2560 + g * 128 + dt * 32 + tx];
  }
  __syncthreads();
#pragma unroll
  for (int q2 = 0; q2 < 4; ++q2) {
    int d = dt * 32 + ty + q2 * 8;
    Vt[(int64_t)(bg * 128 + d) * 2048 + tt * 32 + tx] = tile[tx][ty + q2 * 8];
  }
}

__global__ void concat_bias(const float* __restrict__ bq,
                            const float* __restrict__ bk,
                            const float* __restrict__ bv,
                            float* __restrict__ o) {
  int i = blockIdx.x * 256 + threadIdx.x;
  if (i < 3072)
    o[i] = i < 2048 ? bq[i] : (i < 2560 ? bk[i - 2048] : bv[i - 2560]);
}

// ---------------------------------------------------------------------------
extern "C" void kernel_launch(void* const* d_in, const int* in_sizes, int n_in,
                              void* d_out, int out_size, void* d_ws,
                              size_t ws_size, hipStream_t stream) {
  const float* x = (const float*)d_in[0];
  const float* Wq = (const float*)d_in[1];
  const float* bq = (const float*)d_in[2];
  const float* Wk = (const float*)d_in[3];
  const float* bk = (const float*)d_in[4];
  const float* Wv = (const float*)d_in[5];
  const float* bv = (const float*)d_in[6];
  const float* Wo = (const float*)d_in[7];
  const float* bo = (const float*)d_in[8];
  float* out = (float*)d_out;

  char* ws = (char*)d_ws;
  bf16* xb = (bf16*)(ws);
  bf16* wqkvT = (bf16*)(ws + 16777216);
  bf16* woT = (bf16*)(ws + 29360128);
  float* bqkv = (float*)(ws + 37748736);
  bf16* qkv = (bf16*)(ws + 37761024);
  bf16* vt = (bf16*)(ws + 62926848);
  bf16* attnb = (bf16*)(ws + 67121152);

  convert_x<<<8192, 256, 0, stream>>>(x, xb);
  dim3 tb(32, 8);
  transpose_w<<<dim3(64, 64), tb, 0, stream>>>(Wq, wqkvT, 2048, 2048);
  transpose_w<<<dim3(16, 64), tb, 0, stream>>>(Wk, wqkvT + 2048 * 2048, 2048, 512);
  transpose_w<<<dim3(16, 64), tb, 0, stream>>>(Wv, wqkvT + 2560 * 2048, 2048, 512);
  transpose_w<<<dim3(64, 64), tb, 0, stream>>>(Wo, woT, 2048, 2048);
  concat_bias<<<12, 256, 0, stream>>>(bq, bk, bv, bqkv);

  gemm_bt<false><<<dim3(24, 32), 256, 0, stream>>>(xb, wqkvT, bqkv, qkv, 4096,
                                                   3072, 2048);
  transpose_v<<<dim3(4, 64, 8), tb, 0, stream>>>(qkv, vt);
  attn<<<dim3(16, 16, 2), 256, 0, stream>>>(qkv, vt, attnb);
  gemm_bt<true><<<dim3(16, 32), 256, 0, stream>>>(attnb, woT, bo, out, 4096,
                                                  2048, 2048);
}